// Round 8
// baseline (310.981 us; speedup 1.0000x reference)
//
#include <hip/hip_runtime.h>

// Pipeline (6 kernels):
//   k_prep_a : images/tag f32 -> Abf bf16 (grid-stride pure-BW streaming kernel)
//   k_prep_w : attn_W -> Wa bf16, fc_W -> Wf bf16 (remapped, gap zero), regP = 0
//   k_gemm1  : region = Abf(imgtag) @ Wa^T. BM=64, K-SPLIT 4 (grid 576), ALL staging
//              via gl16 (A from L3-resident Abf, B from L2-resident Wa), atomicAdd
//              combine into regP.
//   k_attn   : tanh-softmax attention from regP, boxfeat -> Abf cols 2048..2303
//   k_gemm2  : dout = Abf @ Wf^T, 144x128 tile, 384 thr, grid 512 = exactly 2 blocks/CU
//   k_norm   : bias + L2 normalize in place
// Workspace (71,753,728 B -- must stay < ~79 MB, R6's 94.8 MB killed the container):
//   Abf[9216][3072] bf16 | Wf[1024][3072] bf16 | Wa[208][2816] bf16 | regP[9216][208] f32
//
// LESSONS: (R3) dbuf+1-barrier kills blocks/CU; __syncthreads drains vmcnt(0) anyway.
// (R2) B direct L2->reg puts scattered-load latency on the MFMA chain.
// (R7) in-loop f32 A-loads (fused convert) put HBM latency on every K-step's barrier
// at ~1.4 blocks/CU -> un-fuse: convert in a streaming kernel, GEMM stages bf16 via gl16.

#define M_TOT 9216
#define K1    2816
#define K2    3072
#define ES    1024

typedef __attribute__((ext_vector_type(8))) short bf16x8;
typedef __attribute__((ext_vector_type(4))) float floatx4;

static __device__ __forceinline__ unsigned short f2bf(float f) {
    unsigned int u = __float_as_uint(f);
    u += 0x7fffu + ((u >> 16) & 1u);   // RNE
    return (unsigned short)(u >> 16);
}

static __device__ __forceinline__ void cvt8(const float* __restrict__ g,
                                            unsigned short* __restrict__ d) {
    const float4 f0 = *(const float4*)g;
    const float4 f1 = *(const float4*)(g + 4);
    uint4 pk;
    pk.x = (unsigned)f2bf(f0.x) | ((unsigned)f2bf(f0.y) << 16);
    pk.y = (unsigned)f2bf(f0.z) | ((unsigned)f2bf(f0.w) << 16);
    pk.z = (unsigned)f2bf(f1.x) | ((unsigned)f2bf(f1.y) << 16);
    pk.w = (unsigned)f2bf(f1.z) | ((unsigned)f2bf(f1.w) << 16);
    *(uint4*)d = pk;
}

// async global->LDS, 16 B per lane; LDS dest must be wave-uniform base (+lane*16)
static __device__ __forceinline__ void gl16(const void* g, const void* l) {
    __builtin_amdgcn_global_load_lds(
        (const __attribute__((address_space(1))) unsigned int*)g,
        (__attribute__((address_space(3))) unsigned int*)(unsigned int)(unsigned long long)l,
        16, 0, 0);
}

// ============ prep A: images/tag f32 -> Abf bf16, grid-stride streaming ============
#define NC_ABF (9216 * 352)
__global__ __launch_bounds__(256) void k_prep_a(
    const float* __restrict__ images,   // [9216][2048]
    const float* __restrict__ tag,      // [9216][768]
    unsigned short* __restrict__ Abf)   // [9216][3072]
{
    const int stride = gridDim.x * 256;
    for (int u = blockIdx.x * 256 + threadIdx.x; u < NC_ABF; u += stride) {
        const int m = u / 352;
        const int c = u - m * 352;
        if (c < 256) cvt8(images + (long)m * 2048 + c * 8, Abf + (long)m * K2 + c * 8);
        else         cvt8(tag + (long)m * 768 + (c - 256) * 8,
                          Abf + (long)m * K2 + 2304 + (c - 256) * 8);
    }
}

// ============ prep weights + regP zero ============
#define NC_WF  (1024 * 384)
#define NC_WA  ( 208 * 352)
#define NC_RP  (9216 * 208 / 4)     // 479,232 uint4 chunks of regP
__global__ __launch_bounds__(256) void k_prep_w(
    const float* __restrict__ attn_W,   // [200][2816]
    const float* __restrict__ fc_W,     // [1024][3016]
    unsigned short* __restrict__ Wa,    // [208][2816]
    unsigned short* __restrict__ Wf,    // [1024][3072]
    float* __restrict__ regP)           // [9216][208] -> zeroed
{
    const int u = blockIdx.x * 256 + threadIdx.x;
    uint4 z; z.x = z.y = z.z = z.w = 0u;
    if (u < NC_WF) {
        const int r = u / 384;
        const int dc = (u - r * 384) * 8;
        unsigned short* d = Wf + (long)r * K2 + dc;
        if (dc < 2248)      cvt8(fc_W + (long)r * 3016 + dc, d);        // img+box cols
        else if (dc < 2304) *(uint4*)d = z;                             // zero gap
        else                cvt8(fc_W + (long)r * 3016 + (dc - 56), d); // tag cols
    } else if (u < NC_WF + NC_WA) {
        const int v = u - NC_WF;
        const int r = v / 352;
        const int c = (v - r * 352) * 8;
        if (r < 200) cvt8(attn_W + (long)r * K1 + c, Wa + (long)r * K1 + c);
        else         *(uint4*)(Wa + (long)r * K1 + c) = z;
    } else if (u < NC_WF + NC_WA + NC_RP) {
        ((uint4*)regP)[u - NC_WF - NC_WA] = z;
    }
}

// ============ GEMM1: region, BM=64, K-split 4, all-gl16 staging ============
// grid 576 x 256. Block (bid>>2 = m-tile of 64 rows, bid&3 = K-quarter of 704).
// 34 gl16 units/step: 0..7 = A rows (from Abf bf16), 8..33 = B rows (Wa).
__global__ __launch_bounds__(256, 4) void k_gemm1(
    const unsigned short* __restrict__ Abf,   // [9216][3072] bf16 (img/tag cols)
    const unsigned short* __restrict__ Wa,    // [208][2816] bf16
    float* __restrict__ regP)                 // [9216][208] f32, pre-zeroed
{
    __shared__ __align__(16) unsigned short ldsA[64 * 64];    //  8,192 B
    __shared__ __align__(16) unsigned short ldsB[208 * 64];   // 26,624 B

    const int t = threadIdx.x;
    const int lane = t & 63;
    const int w = t >> 6;
    const int quad = lane >> 4;
    const int ln15 = lane & 15;
    const int x7 = ln15 & 7;
    const int bid = blockIdx.x;
    const int m0 = (bid >> 2) * 64;
    const int kh = bid & 3;
    const int kbase = kh * 704;                 // 11 K-steps per quarter
    const int lrow = lane >> 3;
    const int schunk = (lane & 7) ^ lrow;       // inverse-swizzled source 16B chunk

    floatx4 acc[13] = {};

    for (int kt = 0; kt < 11; ++kt) {
        const int kb = kbase + kt * 64;
        const int acol = kb + ((kb >= 2048) ? 256 : 0);   // skip boxfeat gap in Abf
#pragma unroll
        for (int i = 0; i < 9; ++i) {
            const int u = w + i * 4;            // 34 units: 0..7 = A, 8..33 = B
            if (u < 8) {
                gl16(Abf + (long)(m0 + u * 8 + lrow) * K2 + acol + schunk * 8,
                     ldsA + u * 512);
            } else if (u < 34) {
                gl16(Wa + (long)((u - 8) * 8 + lrow) * K1 + kb + schunk * 8,
                     ldsB + (u - 8) * 512);
            }
        }
        __syncthreads();
        // wave w computes rows w*16..w*16+15 x all 13 j-tiles
#pragma unroll
        for (int s = 0; s < 2; ++s) {
            const int g = s * 4 + quad;
            const int co = (g ^ x7) << 3;
            const bf16x8 a = *(const bf16x8*)&ldsA[(w * 16 + ln15) * 64 + co];
#pragma unroll
            for (int j = 0; j < 13; ++j) {
                const bf16x8 b = *(const bf16x8*)&ldsB[(j * 16 + ln15) * 64 + co];
                acc[j] = __builtin_amdgcn_mfma_f32_16x16x32_bf16(a, b, acc[j], 0, 0, 0);
            }
        }
        __syncthreads();
    }

    // partial -> regP via atomicAdd (device-scope; 4 addends per address)
#pragma unroll
    for (int j = 0; j < 13; ++j)
#pragma unroll
        for (int r = 0; r < 4; ++r)
            atomicAdd(&regP[(long)(m0 + w * 16 + quad * 4 + r) * 208 + j * 16 + ln15],
                      acc[j][r]);
}

// ============ attention: one row per wave, grid 2304 x 256 ============
__global__ __launch_bounds__(256, 4) void k_attn(
    const float* __restrict__ regP,     // [9216][208]
    const float* __restrict__ boxes,    // [9216][30]
    const float* __restrict__ pos_emb,  // [257][200]
    unsigned short* __restrict__ Abf)   // writes cols 2048..2303
{
    const int t = threadIdx.x;
    const int lane = t & 63;
    const int w = t >> 6;
    const int m = blockIdx.x * 4 + w;

    const float* r0 = regP + (long)m * 208;
    float rv[4];
#pragma unroll
    for (int c = 0; c < 4; ++c) {
        const int e = lane + c * 64;
        rv[c] = (e < 200) ? r0[e] : 0.0f;
    }
    const float* bx = boxes + (long)m * 30;
    int idx[15]; float bw[15], sc_[15];
#pragma unroll
    for (int k = 0; k < 15; ++k) {
        int ii = (int)bx[k];
        idx[k] = (ii < 0) ? 0 : (ii > 256 ? 256 : ii);
        bw[k] = bx[15 + k];
    }
#pragma unroll
    for (int k = 0; k < 15; ++k) {
        const float* em = pos_emb + (long)idx[k] * 200;
        float p = 0.0f;
#pragma unroll
        for (int c = 0; c < 4; ++c) {
            const int e = lane + c * 64;
            if (e < 200) p += rv[c] * em[e];
        }
        for (int off = 32; off; off >>= 1) p += __shfl_xor(p, off, 64);
        sc_[k] = p;
    }
    float mx = -1e30f;
#pragma unroll
    for (int k = 0; k < 15; ++k) { sc_[k] = tanhf(sc_[k]); mx = fmaxf(mx, sc_[k]); }
    float Z = 0.0f, den = 0.0f, pk[15];
#pragma unroll
    for (int k = 0; k < 15; ++k) { pk[k] = __expf(sc_[k] - mx); Z += pk[k]; }
#pragma unroll
    for (int k = 0; k < 15; ++k) { pk[k] *= bw[k]; den += pk[k]; }
    den += 1e-6f * Z;                 // softmax*w / (sum + eps) exactly
    const float inv = 1.0f / den;
    unsigned short* bo = Abf + (long)m * K2 + 2048;
#pragma unroll
    for (int c = 0; c < 4; ++c) {
        const int e = lane + c * 64;
        float o = 0.0f;
        if (e < 200) {
#pragma unroll
            for (int k = 0; k < 15; ++k) o += pk[k] * pos_emb[(long)idx[k] * 200 + e];
            o *= inv;
        }
        bo[e] = f2bf(o);              // cols 200..255 exact 0 (x*garbage would NaN)
    }
}

// ============ GEMM2: dout(f32) = Abf[9216][3072] @ Wf^T ============
// 144x128 tile, 384 threads (3m x 2n waves), grid 512 = exactly 2 blocks/CU (balanced).
// nx = bid&7 -> one Wf N-panel per XCD L2.
__global__ __launch_bounds__(384, 3) void k_gemm2(
    const unsigned short* __restrict__ Abf,
    const unsigned short* __restrict__ Wf,
    float* __restrict__ dout)
{
    __shared__ __align__(16) unsigned short ldsA[144 * 64];   // 18,432 B
    __shared__ __align__(16) unsigned short ldsB[128 * 64];   // 16,384 B
    const int t = threadIdx.x;
    const int lane = t & 63;
    const int w = t >> 6;                 // 0..5
    const int quad = lane >> 4;
    const int ln15 = lane & 15;
    const int x7 = ln15 & 7;
    const int nx = blockIdx.x & 7;        // 8 XCDs round-robin consecutive bids
    const int mx = blockIdx.x >> 3;       // 0..63
    const int m0 = mx * 144;
    const int n0 = nx * 128;
    const int lrow = lane >> 3;
    const int schunk = (lane & 7) ^ lrow;
    const int wm = (w % 3) * 48;
    const int wn = (w / 3) * 64;

    floatx4 acc[3][4] = {};

    for (int kt = 0; kt < 48; ++kt) {
        const int kb = kt * 64;
#pragma unroll
        for (int i = 0; i < 6; ++i) {
            const int u = w + i * 6;      // 34 units: 0..17 = A (144 rows), 18..33 = B (128)
            if (u < 18)
                gl16(Abf + (long)(m0 + u * 8 + lrow) * K2 + kb + schunk * 8, ldsA + u * 512);
            else if (u < 34)
                gl16(Wf + (long)(n0 + (u - 18) * 8 + lrow) * K2 + kb + schunk * 8,
                     ldsB + (u - 18) * 512);
        }
        __syncthreads();
#pragma unroll
        for (int s = 0; s < 2; ++s) {
            const int g = s * 4 + quad;
            const int co = (g ^ x7) << 3;
            bf16x8 a[3], b[4];
#pragma unroll
            for (int i = 0; i < 3; ++i)
                a[i] = *(const bf16x8*)&ldsA[(wm + i * 16 + ln15) * 64 + co];
#pragma unroll
            for (int j = 0; j < 4; ++j)
                b[j] = *(const bf16x8*)&ldsB[(wn + j * 16 + ln15) * 64 + co];
#pragma unroll
            for (int i = 0; i < 3; ++i)
#pragma unroll
                for (int j = 0; j < 4; ++j)
                    acc[i][j] = __builtin_amdgcn_mfma_f32_16x16x32_bf16(a[i], b[j], acc[i][j], 0, 0, 0);
        }
        __syncthreads();
    }
#pragma unroll
    for (int i = 0; i < 3; ++i)
#pragma unroll
        for (int j = 0; j < 4; ++j) {
            const int row = m0 + wm + i * 16 + quad * 4;
            const int col = n0 + wn + j * 16 + ln15;
#pragma unroll
            for (int r = 0; r < 4; ++r)
                dout[(long)(row + r) * ES + col] = acc[i][j][r];
        }
}

// ============ bias + L2 normalize, IN-PLACE in d_out (f32) ============
__global__ __launch_bounds__(256) void k_norm(
    float* __restrict__ dout,
    const float* __restrict__ bias)
{
    __shared__ float red[4];
    const int m = blockIdx.x;
    const int t = threadIdx.x;
    float* f = dout + (long)m * ES + t * 4;
    float4 v = *(const float4*)f;
    const float4 bs = *(const float4*)(bias + t * 4);
    v.x += bs.x; v.y += bs.y; v.z += bs.z; v.w += bs.w;
    float ss = v.x * v.x + v.y * v.y + v.z * v.z + v.w * v.w;
    for (int off = 32; off; off >>= 1) ss += __shfl_xor(ss, off, 64);
    if ((t & 63) == 0) red[t >> 6] = ss;
    __syncthreads();
    const float total = red[0] + red[1] + red[2] + red[3];
    const float inv = 1.0f / (sqrtf(total) + 1e-8f);
    float4 o;
    o.x = v.x * inv; o.y = v.y * inv; o.z = v.z * inv; o.w = v.w * inv;
    *(float4*)f = o;
}

// ============ launch ============
extern "C" void kernel_launch(void* const* d_in, const int* in_sizes, int n_in,
                              void* d_out, int out_size, void* d_ws, size_t ws_size,
                              hipStream_t stream) {
    const float* images  = (const float*)d_in[0];
    const float* tag     = (const float*)d_in[1];
    const float* boxes   = (const float*)d_in[2];
    const float* pos_emb = (const float*)d_in[3];
    const float* attn_W  = (const float*)d_in[4];
    const float* fc_W    = (const float*)d_in[5];
    const float* fc_b    = (const float*)d_in[6];
    float* out = (float*)d_out;

    unsigned short* Abf = (unsigned short*)d_ws;            // 56,623,104 B
    unsigned short* Wf  = Abf + (size_t)M_TOT * K2;         //  6,291,456 B
    unsigned short* Wa  = Wf  + (size_t)ES * K2;            //  1,171,456 B
    float* regP = (float*)(Wa + (size_t)208 * K1);          //  7,667,712 B
    // total workspace: 71,753,728 B

    k_prep_a<<<4096, 256, 0, stream>>>(images, tag, Abf);
    k_prep_w<<<(NC_WF + NC_WA + NC_RP + 255) / 256, 256, 0, stream>>>(
        attn_W, fc_W, Wa, Wf, (float*)regP);
    k_gemm1 <<<576, 256, 0, stream>>>(Abf, Wa, regP);
    k_attn  <<<2304, 256, 0, stream>>>(regP, boxes, pos_emb, Abf);
    k_gemm2 <<<512, 384, 0, stream>>>(Abf, Wf, out);
    k_norm  <<<M_TOT, 256, 0, stream>>>(out, fc_b);
}